// Round 11
// baseline (163.259 us; speedup 1.0000x reference)
//
#include <hip/hip_runtime.h>
#include <hip/hip_bf16.h>
#include <math.h>

#define PI_F 3.14159265358979f

typedef __attribute__((ext_vector_type(8))) short bf16x8;   // 8 bf16
typedef __attribute__((ext_vector_type(4))) float f32x4;
typedef __attribute__((ext_vector_type(2))) float f32x2;

#define DM 512
#define LSEQ 2048
#define NB 8
#define NFFT 4096
#define MTOK (NB*LSEQ)

__device__ __forceinline__ float frcp(float x) { return __builtin_amdgcn_rcpf(x); }

// Exact-enough GELU: tanh form, tanh via v_exp. |err vs erf-GELU| <~ 1e-3.
__device__ __forceinline__ float gelu_fast(float y) {
  float t = 0.79788456f * (y + 0.044715f * y * y * y);
  float e = __expf(2.0f * t);
  float th = 1.0f - 2.0f * frcp(e + 1.0f);
  return 0.5f * y * (1.0f + th);
}

// Padded LDS index (split f32 arrays): +1 word per 32.
__device__ __forceinline__ int PD(int i) { return i + (i >> 5); }
#define LDSN 4224   // PD(4095)=4222

// ---------------- 8-point DFT in registers (proven r2-r10) ----------------
template<bool INV>
__device__ __forceinline__ void dft8(const float xr[8], const float xi[8],
                                     float yr[8], float yi[8]) {
  const float C = 0.70710678118654752f;
  float t0r=xr[0]+xr[4], t0i=xi[0]+xi[4];
  float t1r=xr[0]-xr[4], t1i=xi[0]-xi[4];
  float t2r=xr[2]+xr[6], t2i=xi[2]+xi[6];
  float t3r=xr[2]-xr[6], t3i=xi[2]-xi[6];
  float it3r = INV ? -t3i : t3i;
  float it3i = INV ?  t3r : -t3r;
  float E0r=t0r+t2r, E0i=t0i+t2i;
  float E2r=t0r-t2r, E2i=t0i-t2i;
  float E1r=t1r+it3r, E1i=t1i+it3i;
  float E3r=t1r-it3r, E3i=t1i-it3i;
  float u0r=xr[1]+xr[5], u0i=xi[1]+xi[5];
  float u1r=xr[1]-xr[5], u1i=xi[1]-xi[5];
  float u2r=xr[3]+xr[7], u2i=xi[3]+xi[7];
  float u3r=xr[3]-xr[7], u3i=xi[3]-xi[7];
  float iu3r = INV ? -u3i : u3i;
  float iu3i = INV ?  u3r : -u3r;
  float O0r=u0r+u2r, O0i=u0i+u2i;
  float O2r=u0r-u2r, O2i=u0i-u2i;
  float O1r=u1r+iu3r, O1i=u1i+iu3i;
  float O3r=u1r-iu3r, O3i=u1i-iu3i;
  float w1r = INV ? C*(O1r-O1i) : C*(O1r+O1i);
  float w1i = INV ? C*(O1r+O1i) : C*(O1i-O1r);
  float w2r = INV ? -O2i : O2i;
  float w2i = INV ?  O2r : -O2r;
  float w3r = INV ? -C*(O3r+O3i) : C*(O3i-O3r);
  float w3i = INV ?  C*(O3r-O3i) : -C*(O3r+O3i);
  yr[0]=E0r+O0r; yi[0]=E0i+O0i;
  yr[4]=E0r-O0r; yi[4]=E0i-O0i;
  yr[1]=E1r+w1r; yi[1]=E1i+w1i;
  yr[5]=E1r-w1r; yi[5]=E1i-w1i;
  yr[2]=E2r+w2r; yi[2]=E2i+w2i;
  yr[6]=E2r-w2r; yi[6]=E2i-w2i;
  yr[3]=E3r+w3r; yi[3]=E3i+w3i;
  yr[7]=E3r-w3r; yi[7]=E3i-w3i;
}

// ---------------- 16-point DFT = 2 x dft8 + combine ----------------
template<bool INV>
__device__ __forceinline__ void dft16(const float xr[16], const float xi[16],
                                      float yr[16], float yi[16]) {
  float exr[8], exi[8], oxr[8], oxi[8];
  #pragma unroll
  for (int m = 0; m < 8; ++m) {
    exr[m]=xr[2*m];   exi[m]=xi[2*m];
    oxr[m]=xr[2*m+1]; oxi[m]=xi[2*m+1];
  }
  float er[8], ei[8], orr[8], oii[8];
  dft8<INV>(exr, exi, er, ei);
  dft8<INV>(oxr, oxi, orr, oii);
  const float KC = 0.92387953251128675f;
  const float KS = 0.38268343236508977f;
  const float KH = 0.70710678118654752f;
  float tr, ti;
  yr[0]=er[0]+orr[0]; yi[0]=ei[0]+oii[0];
  yr[8]=er[0]-orr[0]; yi[8]=ei[0]-oii[0];
  { float a=KC, b=INV?KS:-KS;
    tr=orr[1]*a-oii[1]*b; ti=orr[1]*b+oii[1]*a;
    yr[1]=er[1]+tr; yi[1]=ei[1]+ti; yr[9]=er[1]-tr; yi[9]=ei[1]-ti; }
  { float a=KH, b=INV?KH:-KH;
    tr=orr[2]*a-oii[2]*b; ti=orr[2]*b+oii[2]*a;
    yr[2]=er[2]+tr; yi[2]=ei[2]+ti; yr[10]=er[2]-tr; yi[10]=ei[2]-ti; }
  { float a=KS, b=INV?KC:-KC;
    tr=orr[3]*a-oii[3]*b; ti=orr[3]*b+oii[3]*a;
    yr[3]=er[3]+tr; yi[3]=ei[3]+ti; yr[11]=er[3]-tr; yi[11]=ei[3]-ti; }
  { if (INV) { tr=-oii[4]; ti= orr[4]; } else { tr= oii[4]; ti=-orr[4]; }
    yr[4]=er[4]+tr; yi[4]=ei[4]+ti; yr[12]=er[4]-tr; yi[12]=ei[4]-ti; }
  { float a=-KS, b=INV?KC:-KC;
    tr=orr[5]*a-oii[5]*b; ti=orr[5]*b+oii[5]*a;
    yr[5]=er[5]+tr; yi[5]=ei[5]+ti; yr[13]=er[5]-tr; yi[13]=ei[5]-ti; }
  { float a=-KH, b=INV?KH:-KH;
    tr=orr[6]*a-oii[6]*b; ti=orr[6]*b+oii[6]*a;
    yr[6]=er[6]+tr; yi[6]=ei[6]+ti; yr[14]=er[6]-tr; yi[14]=ei[6]-ti; }
  { float a=-KC, b=INV?KS:-KS;
    tr=orr[7]*a-oii[7]*b; ti=orr[7]*b+oii[7]*a;
    yr[7]=er[7]+tr; yi[7]=ei[7]+ti; yr[15]=er[7]-tr; yi[15]=ei[7]-ti; }
}

// ---------------- Stockham radix-16 stage (chain twiddle; fftK path) -------
template<bool INV, int NSLOG, int NBF>
__device__ __forceinline__ void r16s(float* sr, float* si, int tid,
                                     float c1, float s1f) {
  float yr[16], yi[16];
  bool act = (NBF >= 256) || (tid < NBF);
  __syncthreads();
  if (act) {
    float xr[16], xi[16];
    #pragma unroll
    for (int m = 0; m < 16; ++m) {
      int ix = PD(tid + m * NBF);
      xr[m] = sr[ix]; xi[m] = si[ix];
    }
    if (NSLOG > 0) {
      float s1 = INV ? -s1f : s1f;
      float wr = c1, wi = s1;
      #pragma unroll
      for (int m = 1; m < 16; ++m) {
        float tr = xr[m]*wr - xi[m]*wi;
        float ti = xr[m]*wi + xi[m]*wr;
        xr[m] = tr; xi[m] = ti;
        float nr = wr*c1 - wi*s1;
        float ni = wr*s1 + wi*c1;
        wr = nr; wi = ni;
      }
    }
    dft16<INV>(xr, xi, yr, yi);
  }
  __syncthreads();
  if (act) {
    int r = tid & ((1 << NSLOG) - 1);
    int q = tid >> NSLOG;
    int base = (q << (NSLOG + 4)) + r;
    #pragma unroll
    for (int p = 0; p < 16; ++p) {
      int ix = PD(base + (p << NSLOG));
      sr[ix] = yr[p]; si[ix] = yi[p];
    }
  }
}

// ---------------- Stockham radix-16 stage with PRECOMPUTED twiddle powers --
// twr/twi hold w^1..w^15 of the FORWARD base; INV conjugates at use (free).
template<bool INV, int NSLOG>
__device__ __forceinline__ void r16s_tw(float* sr, float* si, int tid,
                                        const float* twr, const float* twi) {
  float yr[16], yi[16];
  __syncthreads();
  {
    float xr[16], xi[16];
    #pragma unroll
    for (int m = 0; m < 16; ++m) {
      int ix = PD(tid + m * 256);
      xr[m] = sr[ix]; xi[m] = si[ix];
    }
    if (NSLOG > 0) {
      #pragma unroll
      for (int m = 1; m < 16; ++m) {
        float wr = twr[m-1];
        float wi = INV ? -twi[m-1] : twi[m-1];
        float tr = xr[m]*wr - xi[m]*wi;
        float ti = xr[m]*wi + xi[m]*wr;
        xr[m] = tr; xi[m] = ti;
      }
    }
    dft16<INV>(xr, xi, yr, yi);
  }
  __syncthreads();
  {
    int r = tid & ((1 << NSLOG) - 1);
    int q = tid >> NSLOG;
    int base = (q << (NSLOG + 4)) + r;
    #pragma unroll
    for (int p = 0; p < 16; ++p) {
      int ix = PD(base + (p << NSLOG));
      sr[ix] = yr[p]; si[ix] = yi[p];
    }
  }
}

// build w^1..w^15 (same sequential-product numerics as the old in-stage chain)
__device__ __forceinline__ void tw_powers(float c, float s,
                                          float* twr, float* twi) {
  twr[0] = c; twi[0] = s;
  #pragma unroll
  for (int m = 1; m < 15; ++m) {
    twr[m] = twr[m-1]*c - twi[m-1]*s;
    twi[m] = twr[m-1]*s + twi[m-1]*c;
  }
}

// ---- Stage 0 of a FORWARD 4096 FFT whose inputs [2048,4096) are ZERO ----
__device__ __forceinline__ void r16s_zfirst(float* sr, float* si, int tid) {
  const float KC = 0.92387953251128675f;
  const float KS = 0.38268343236508977f;
  const float KH = 0.70710678118654752f;
  float xr[8], xi[8];
  __syncthreads();
  #pragma unroll
  for (int m = 0; m < 8; ++m) {
    int ix = PD(tid + m * 256);
    xr[m] = sr[ix]; xi[m] = si[ix];
  }
  float er[8], ei[8];
  dft8<false>(xr, xi, er, ei);
  float tr[8], ti[8];
  tr[0] = xr[0];                      ti[0] = xi[0];
  tr[1] =  xr[1]*KC + xi[1]*KS;       ti[1] =  xi[1]*KC - xr[1]*KS;
  tr[2] = (xr[2] + xi[2])*KH;         ti[2] = (xi[2] - xr[2])*KH;
  tr[3] =  xr[3]*KS + xi[3]*KC;       ti[3] =  xi[3]*KS - xr[3]*KC;
  tr[4] =  xi[4];                     ti[4] = -xr[4];
  tr[5] = -xr[5]*KS + xi[5]*KC;       ti[5] = -xi[5]*KS - xr[5]*KC;
  tr[6] = (xi[6] - xr[6])*KH;         ti[6] = -(xr[6] + xi[6])*KH;
  tr[7] = -xr[7]*KC + xi[7]*KS;       ti[7] = -xi[7]*KC - xr[7]*KS;
  float odr[8], odi[8];
  dft8<false>(tr, ti, odr, odi);
  __syncthreads();
  int base = tid << 4;
  #pragma unroll
  for (int j = 0; j < 8; ++j) {
    int ie = PD(base + 2*j), io = PD(base + 2*j + 1);
    sr[ie] = er[j];  si[ie] = ei[j];
    sr[io] = odr[j]; si[io] = odi[j];
  }
}

// ---------------- Stockham radix-8 stage (256-thread blocks) --------------
template<bool INV, int NSLOG, int NBF>
__device__ __forceinline__ void r8s(float* sr, float* si, int tid,
                                    float c1, float s1f) {
  float yr[8], yi[8];
  bool act = (NBF >= 256) || (tid < NBF);
  __syncthreads();
  if (act) {
    float xr[8], xi[8];
    #pragma unroll
    for (int m = 0; m < 8; ++m) {
      int ix = PD(tid + m * NBF);
      xr[m] = sr[ix]; xi[m] = si[ix];
    }
    if (NSLOG > 0) {
      float s1 = INV ? -s1f : s1f;
      float wr = c1, wi = s1;
      #pragma unroll
      for (int m = 1; m < 8; ++m) {
        float tr = xr[m]*wr - xi[m]*wi;
        float ti = xr[m]*wi + xi[m]*wr;
        xr[m] = tr; xi[m] = ti;
        float nr = wr*c1 - wi*s1;
        float ni = wr*s1 + wi*c1;
        wr = nr; wi = ni;
      }
    }
    dft8<INV>(xr, xi, yr, yi);
  }
  __syncthreads();
  if (act) {
    int r = tid & ((1 << NSLOG) - 1);
    int q = tid >> NSLOG;
    int base = (q << (NSLOG + 3)) + r;
    #pragma unroll
    for (int p = 0; p < 8; ++p) {
      int ix = PD(base + (p << NSLOG));
      sr[ix] = yr[p]; si[ix] = yi[p];
    }
  }
}

// 4096 full, cached twiddles (conv path)
template<bool INV>
__device__ __forceinline__ void fft4096t(float* sr, float* si, int tid,
    const float* twAr, const float* twAi, const float* twBr, const float* twBi) {
  r16s_tw<INV, 0>(sr, si, tid, twAr, twAi);
  r16s_tw<INV, 4>(sr, si, tid, twAr, twAi);
  r16s_tw<INV, 8>(sr, si, tid, twBr, twBi);
  __syncthreads();
}

// forward 4096 with inputs [2048,4096) == 0, cached twiddles (conv path)
__device__ __forceinline__ void fft4096tz(float* sr, float* si, int tid,
    const float* twAr, const float* twAi, const float* twBr, const float* twBi) {
  r16s_zfirst(sr, si, tid);
  r16s_tw<false, 4>(sr, si, tid, twAr, twAi);
  r16s_tw<false, 8>(sr, si, tid, twBr, twBi);
  __syncthreads();
}

// 4096 chain-twiddle (fftK path, low reuse)
__device__ __forceinline__ void fft4096z(float* sr, float* si, int tid,
                                         float cA, float sA, float cB, float sB) {
  r16s_zfirst(sr, si, tid);
  r16s<false, 4, 256>(sr, si, tid, cA, sA);
  r16s<false, 8, 256>(sr, si, tid, cB, sB);
  __syncthreads();
}

// 2048 = 8*16*16, 256 threads
template<bool INV>
__device__ __forceinline__ void fft2048(float* sr, float* si, int tid,
                                        float cA, float sA, float cB, float sB) {
  r8s <INV, 0, 256>(sr, si, tid, 1.f, 0.f);
  r16s<INV, 3, 128>(sr, si, tid, cA, sA);
  r16s<INV, 7, 128>(sr, si, tid, cB, sB);
  __syncthreads();
}

// ---------------- Kernel 0: wtab prep + omega table ------------------------
// otab[l] = (cr, ci, gbr, gbi): c = 2/(1+w), g = (2/step)*(gbr,gbi).
// PRECISE sincosf (Nyquist l=1024 NaN trap -- round 3); frcp identical to
// the old in-cauchy path so numerics are unchanged.
__global__ __launch_bounds__(256) void k_prep(
    const float* __restrict__ lam_re, const float* __restrict__ lam_im,
    const float* __restrict__ p_re,   const float* __restrict__ p_im,
    const float* __restrict__ B_re,   const float* __restrict__ B_im,
    const float* __restrict__ Ct_re,  const float* __restrict__ Ct_im,
    float* __restrict__ wtab, float4* __restrict__ otab) {
  int bidx = blockIdx.x;
  if (bidx < 128) {
    int idx = bidx * 256 + threadIdx.x;   // h*64+n
    int n = idx & 63;
    float br = B_re[idx],  bi = B_im[idx];
    float cr = Ct_re[idx], ci = Ct_im[idx];
    float pr = p_re[n],    pi = p_im[n];
    float* w = wtab + (size_t)idx * 12;
    w[0] = cr*br + ci*bi;   w[1] = cr*bi - ci*br;
    w[2] = cr*pr + ci*pi;   w[3] = cr*pi - ci*pr;
    w[4] = pr*br + pi*bi;   w[5] = pr*bi - pi*br;
    w[6] = pr*pr + pi*pi;   w[7] = lam_re[n];
    w[8] = lam_im[n];       w[9] = 0.f; w[10] = 0.f; w[11] = 0.f;
  } else {
    int l = (bidx - 128) * 256 + threadIdx.x;   // [0,2048)
    float omi, omr;
    sincosf(-2.0f * PI_F * (float)l / (float)LSEQ, &omi, &omr);
    float a = 1.0f + omr;
    float iv = frcp(a*a + omi*omi);
    float4 o;
    o.x = 2.0f * a * iv;                        // cr
    o.y = -2.0f * omi * iv;                     // ci
    o.z = (1.0f - omr*omr - omi*omi) * iv;      // g base re
    o.w = (-2.0f * omi) * iv;                   // g base im
    otab[l] = o;
  }
}

// ---------------- Mega kernel: cauchy | tr_u | W cast (heterogeneous) ------
__global__ __launch_bounds__(256) void k_mega(
    const float* __restrict__ wtab, const float4* __restrict__ otab,
    const float* __restrict__ log_step, float2* __restrict__ atr,
    const float* __restrict__ u, float* __restrict__ ut,
    const float* __restrict__ W, __hip_bfloat16* __restrict__ Wb) {
  __shared__ float tsh[32][33];
  int bidx = blockIdx.x;
  int tid = threadIdx.x;
  if (bidx < 2048) {
    // ---- Cauchy sums, l-pair packed in f32x2 lanes ----
    int h = bidx >> 2;
    int l0 = ((bidx & 3) << 8) + tid;   // [0,1024)
    int l1 = l0 + 1024;
    float tos = 2.0f * expf(-log_step[h]);
    float4 o0 = otab[l0];
    float4 o1 = otab[l1];
    float cr0 = o0.x, ci0 = o0.y, cr1 = o1.x, ci1 = o1.y;
    f32x2 gr, gi;
    gr.x = tos * o0.z;  gr.y = tos * o1.z;
    gi.x = tos * o0.w;  gi.y = tos * o1.w;
    f32x2 K00r={0.f,0.f},K00i={0.f,0.f},K01r={0.f,0.f},K01i={0.f,0.f},
          K10r={0.f,0.f},K10i={0.f,0.f},K11r={0.f,0.f},K11i={0.f,0.f};
    const float4* wq = (const float4*)(wtab + (size_t)h * 64 * 12);
    #pragma unroll 8
    for (int n = 0; n < 64; ++n) {
      float4 wa = wq[n*3+0];
      float4 wb = wq[n*3+1];
      float  lim = wq[n*3+2].x;
      f32x2 dr = gr - wb.w;
      f32x2 di = gi - lim;
      f32x2 den = dr*dr + di*di;
      // paired reciprocal: 1 trans op for both lanes
      float ip = frcp(den.x * den.y);
      f32x2 inv; inv.x = den.y * ip; inv.y = den.x * ip;
      f32x2 car = dr*inv, cai = -di*inv;
      K00r += wa.x*car - wa.y*cai;  K00i += wa.x*cai + wa.y*car;
      K01r += wa.z*car - wa.w*cai;  K01i += wa.z*cai + wa.w*car;
      K10r += wb.x*car - wb.y*cai;  K10i += wb.x*cai + wb.y*car;
      K11r += wb.z*car;             K11i += wb.z*cai;
    }
    {
      float tr = K01r.x*K10r.x - K01i.x*K10i.x, ti = K01r.x*K10i.x + K01i.x*K10r.x;
      float d1r = 1.0f + K11r.x, d1i = K11i.x;
      float invd1 = frcp(d1r*d1r + d1i*d1i);
      float t2r = (tr*d1r + ti*d1i) * invd1;
      float t2i = (ti*d1r - tr*d1i) * invd1;
      float numr = K00r.x - t2r, numi = K00i.x - t2i;
      atr[(size_t)h * LSEQ + l0] = make_float2(cr0*numr - ci0*numi, cr0*numi + ci0*numr);
    }
    {
      float tr = K01r.y*K10r.y - K01i.y*K10i.y, ti = K01r.y*K10i.y + K01i.y*K10r.y;
      float d1r = 1.0f + K11r.y, d1i = K11i.y;
      float invd1 = frcp(d1r*d1r + d1i*d1i);
      float t2r = (tr*d1r + ti*d1i) * invd1;
      float t2i = (ti*d1r - tr*d1i) * invd1;
      float numr = K00r.y - t2r, numi = K00i.y - t2i;
      atr[(size_t)h * LSEQ + l1] = make_float2(cr1*numr - ci1*numi, cr1*numi + ci1*numr);
    }
  } else if (bidx < 2048 + 8192) {
    // ---- transpose u (B,L,D) -> ut (B,D,L), 32x32 tiles ----
    int t = bidx - 2048;
    int lx = t & 63, hy = (t >> 6) & 15, b = t >> 10;
    int l0 = lx * 32, h0 = hy * 32;
    int x = tid & 31, y0 = tid >> 5;
    #pragma unroll
    for (int i = 0; i < 4; ++i) {
      int y = y0 + i*8;
      tsh[y][x] = u[((size_t)b*LSEQ + l0 + y) * DM + h0 + x];
    }
    __syncthreads();
    #pragma unroll
    for (int i = 0; i < 4; ++i) {
      int y = y0 + i*8;
      ut[((size_t)b*DM + h0 + y) * LSEQ + l0 + x] = tsh[x][y];
    }
  } else {
    int i = (bidx - 10240) * 256 + tid;
    Wb[i] = __float2bfloat16(W[i]);
  }
}

// ---------------- Kernel 1b: ifft2048 -> pad -> fft4096 -> Kf --------------
__global__ __launch_bounds__(256, 4) void k_fftK(const float2* __restrict__ atr,
                                                 float2* __restrict__ Kf) {
  __shared__ float sr[LDSN], si[LDSN];
  int h = blockIdx.x, tid = threadIdx.x;
  float c2a, s2a, c2b, s2b, c4a, s4a, c4b, s4b;
  { int r = tid & 7;   __sincosf(-2.f*PI_F*(float)r/128.f,  &s2a, &c2a); }
  { int r = tid & 127; __sincosf(-2.f*PI_F*(float)r/2048.f, &s2b, &c2b); }
  { int r = tid & 15;  __sincosf(-2.f*PI_F*(float)r/256.f,  &s4a, &c4a); }
  { int r = tid;       __sincosf(-2.f*PI_F*(float)r/4096.f, &s4b, &c4b); }
  const float2* ap = atr + (size_t)h * LSEQ;
  #pragma unroll
  for (int i = 0; i < 8; ++i) {
    int l = tid + i*256;
    float2 v = ap[l];
    sr[PD(l)] = v.x; si[PD(l)] = v.y;
  }
  fft2048<true>(sr, si, tid, c2a, s2a, c2b, s2b);
  #pragma unroll
  for (int i = 0; i < 8; ++i) {
    int m = tid + i*256;
    float v = sr[PD(m)] * (1.0f / (float)LSEQ);
    sr[PD(m)] = v;
    si[PD(m)] = 0.0f;
  }
  fft4096z(sr, si, tid, c4a, s4a, c4b, s4b);
  float2* ko = Kf + (size_t)h * NFFT;
  #pragma unroll
  for (int i = 0; i < 16; ++i) {
    int f = tid + i*256;
    ko[f] = make_float2(sr[PD(f)], si[PD(f)]);
  }
}

// ---------------- Kernel 3: FFT conv + D*u + GELU -> zbt (bf16) -----------
__global__ __launch_bounds__(256, 4) void k_conv(const float* __restrict__ ut,
                                                 const float2* __restrict__ Kf,
                                                 const float* __restrict__ Dvec,
                                                 __hip_bfloat16* __restrict__ zbt) {
  __shared__ float sr[LDSN], si[LDSN];
  int wg = blockIdx.x;
  int bp = wg >> 9, h = wg & 511;
  int b0 = bp*2, b1 = bp*2 + 1;
  int tid = threadIdx.x;
  float c4a, s4a, c4b, s4b;
  { int r = tid & 15; __sincosf(-2.f*PI_F*(float)r/256.f,  &s4a, &c4a); }
  { int r = tid;      __sincosf(-2.f*PI_F*(float)r/4096.f, &s4b, &c4b); }
  // precompute twiddle powers once; reused by fwd (as-is) and inv (conjugated)
  float twAr[15], twAi[15], twBr[15], twBi[15];
  tw_powers(c4a, s4a, twAr, twAi);
  tw_powers(c4b, s4b, twBr, twBi);
  const float* u0p = ut + ((size_t)(b0*DM + h)) * LSEQ;
  const float* u1p = ut + ((size_t)(b1*DM + h)) * LSEQ;
  #pragma unroll
  for (int i = 0; i < 8; ++i) {
    int l = tid + i*256;
    sr[PD(l)] = u0p[l];  si[PD(l)] = u1p[l];
  }
  fft4096tz(sr, si, tid, twAr, twAi, twBr, twBi);
  float yrg[16], yig[16];
  const float2* kp = Kf + (size_t)h * NFFT;
  #pragma unroll
  for (int i = 0; i < 16; ++i) {
    int f = tid + i*256;
    int fn = (NFFT - f) & (NFFT - 1);
    float ar = sr[PD(f)],  ai = si[PD(f)];
    float br = sr[PD(fn)], bi = -si[PD(fn)];
    float u0r = 0.5f*(ar + br), u0i = 0.5f*(ai + bi);
    float u1r = 0.5f*(ai - bi), u1i = -0.5f*(ar - br);
    float2 K0 = kp[f];
    float y0r = u0r*K0.x - u0i*K0.y, y0i = u0r*K0.y + u0i*K0.x;
    float y1r = u1r*K0.x - u1i*K0.y, y1i = u1r*K0.y + u1i*K0.x;
    yrg[i] = y0r - y1i;
    yig[i] = y0i + y1r;
  }
  __syncthreads();
  #pragma unroll
  for (int i = 0; i < 16; ++i) {
    int f = tid + i*256;
    sr[PD(f)] = yrg[i]; si[PD(f)] = yig[i];
  }
  fft4096t<true>(sr, si, tid, twAr, twAi, twBr, twBi);
  float d = Dvec[h];
  __hip_bfloat16* zb0 = zbt + ((size_t)(b0*DM + h)) * LSEQ;
  __hip_bfloat16* zb1 = zbt + ((size_t)(b1*DM + h)) * LSEQ;
  const float inv_n = 1.0f / (float)NFFT;
  #pragma unroll
  for (int i = 0; i < 8; ++i) {
    int l = tid + i*256;
    float y0 = sr[PD(l)]*inv_n + d*u0p[l];
    float y1 = si[PD(l)]*inv_n + d*u1p[l];
    zb0[l] = __float2bfloat16(gelu_fast(y0));
    zb1[l] = __float2bfloat16(gelu_fast(y1));
  }
}

// ---------------- Kernel 6: fused GEMM + bias + residual + LayerNorm -------
// 64 tokens x full N=512 per block, 8 waves (2M x 4N). Reads zbt (B,D,L)
// directly with a transposing LDS stage.
__global__ __launch_bounds__(512) void k_gemm_ln(
    const ushort* __restrict__ zbt,   // (B, D, L) bf16
    const short* __restrict__ Wb,     // (O, H) bf16
    const float* __restrict__ bias,
    const float* __restrict__ u,      // (M, D) f32
    const float* __restrict__ lnw, const float* __restrict__ lnb,
    float* __restrict__ out) {
  __shared__ ushort sA[64][40];
  __shared__ short sB[512][40];
  __shared__ float red[2][4][64];
  __shared__ float smu[64], srs[64];
  __shared__ float sln[2][DM];
  int tid = threadIdx.x, wave = tid >> 6, lane = tid & 63;
  int wm = wave >> 2, wn = wave & 3;          // 2 x 4
  int m0 = blockIdx.x * 64;
  int b = m0 >> 11;
  int l0 = m0 & (LSEQ - 1);
  const ushort* zb = zbt + (size_t)b * DM * LSEQ;
  int row = lane & 15, kq8 = (lane >> 4) << 3;
  int kk = tid >> 4, seg = tid & 15;
  int cB = (tid & 3) << 3, rB = tid >> 2;
  sln[0][tid] = lnw[tid];
  sln[1][tid] = lnb[tid];
  f32x4 acc[2][8];
  #pragma unroll
  for (int i = 0; i < 2; ++i)
    #pragma unroll
    for (int j = 0; j < 8; ++j) acc[i][j] = (f32x4){0.f,0.f,0.f,0.f};
  for (int k0 = 0; k0 < DM; k0 += 32) {
    __syncthreads();
    {
      uint2 v = *(const uint2*)(zb + (size_t)(k0 + kk)*LSEQ + l0 + seg*4);
      const ushort* p = (const ushort*)&v;
      sA[seg*4 + 0][kk] = p[0];
      sA[seg*4 + 1][kk] = p[1];
      sA[seg*4 + 2][kk] = p[2];
      sA[seg*4 + 3][kk] = p[3];
    }
    #pragma unroll
    for (int jj = 0; jj < 4; ++jj) {
      int o = rB + jj*128;
      *(uint4*)&sB[o][cB] = *(const uint4*)(Wb + (size_t)o*DM + k0 + cB);
    }
    __syncthreads();
    bf16x8 a0 = *(const bf16x8*)&sA[wm*32 + row][kq8];
    bf16x8 a1 = *(const bf16x8*)&sA[wm*32 + 16 + row][kq8];
    #pragma unroll
    for (int nt = 0; nt < 8; ++nt) {
      bf16x8 bf = *(const bf16x8*)&sB[wn*128 + nt*16 + row][kq8];
      acc[0][nt] = __builtin_amdgcn_mfma_f32_16x16x32_bf16(a0, bf, acc[0][nt], 0, 0, 0);
      acc[1][nt] = __builtin_amdgcn_mfma_f32_16x16x32_bf16(a1, bf, acc[1][nt], 0, 0, 0);
    }
  }
  int ccol = lane & 15, crow = (lane >> 4) << 2;
  #pragma unroll
  for (int rt = 0; rt < 2; ++rt) {
    #pragma unroll
    for (int rr = 0; rr < 4; ++rr) {
      int lr = wm*32 + rt*16 + crow + rr;
      int gr = m0 + lr;
      float ls = 0.f, ls2 = 0.f;
      #pragma unroll
      for (int nt = 0; nt < 8; ++nt) {
        int col = wn*128 + nt*16 + ccol;
        float v = acc[rt][nt][rr] + bias[col] + u[(size_t)gr*DM + col];
        acc[rt][nt][rr] = v;
        ls += v; ls2 += v*v;
      }
      ls  += __shfl_xor(ls, 1);  ls2 += __shfl_xor(ls2, 1);
      ls  += __shfl_xor(ls, 2);  ls2 += __shfl_xor(ls2, 2);
      ls  += __shfl_xor(ls, 4);  ls2 += __shfl_xor(ls2, 4);
      ls  += __shfl_xor(ls, 8);  ls2 += __shfl_xor(ls2, 8);
      if (ccol == 0) { red[0][wn][lr] = ls; red[1][wn][lr] = ls2; }
    }
  }
  __syncthreads();
  if (tid < 64) {
    float s = red[0][0][tid] + red[0][1][tid] + red[0][2][tid] + red[0][3][tid];
    float q = red[1][0][tid] + red[1][1][tid] + red[1][2][tid] + red[1][3][tid];
    float mean = s * (1.0f/(float)DM);
    float var  = q * (1.0f/(float)DM) - mean*mean;
    smu[tid] = mean;
    srs[tid] = rsqrtf(var + 1e-5f);
  }
  __syncthreads();
  #pragma unroll
  for (int rt = 0; rt < 2; ++rt) {
    #pragma unroll
    for (int rr = 0; rr < 4; ++rr) {
      int lr = wm*32 + rt*16 + crow + rr;
      int gr = m0 + lr;
      float mu = smu[lr], rs = srs[lr];
      #pragma unroll
      for (int nt = 0; nt < 8; ++nt) {
        int col = wn*128 + nt*16 + ccol;
        out[(size_t)gr*DM + col] = (acc[rt][nt][rr] - mu) * rs * sln[0][col] + sln[1][col];
      }
    }
  }
}

// ---------------- launch ----------------
extern "C" void kernel_launch(void* const* d_in, const int* in_sizes, int n_in,
                              void* d_out, int out_size, void* d_ws, size_t ws_size,
                              hipStream_t stream) {
  const float* u        = (const float*)d_in[0];
  const float* lam_re   = (const float*)d_in[1];
  const float* lam_im   = (const float*)d_in[2];
  const float* p_re     = (const float*)d_in[3];
  const float* p_im     = (const float*)d_in[4];
  const float* B_re     = (const float*)d_in[5];
  const float* B_im     = (const float*)d_in[6];
  const float* Ct_re    = (const float*)d_in[7];
  const float* Ct_im    = (const float*)d_in[8];
  const float* log_step = (const float*)d_in[9];
  const float* Dv       = (const float*)d_in[10];
  const float* W        = (const float*)d_in[11];
  const float* bias     = (const float*)d_in[12];
  const float* ln_w     = (const float*)d_in[13];
  const float* ln_b     = (const float*)d_in[14];
  float* out = (float*)d_out;
  char* ws = (char*)d_ws;

  // ws: Kf [0,16M) | ut f32 [16,48M) | zbt bf16 [48,64M) | Wb [64,64.5M)
  // atr (8M) + wtab (1.5M) + otab (32K) overlap zbt region (all dead before
  // k_conv writes zbt).
  float2* Kf = (float2*)ws;
  float*  ut = (float*)(ws + (16u << 20));
  __hip_bfloat16* zbt = (__hip_bfloat16*)(ws + (48u << 20));
  float2* atr  = (float2*)(ws + (48u << 20));
  float*  wtab = (float*)(ws + (56u << 20));
  float4* otab = (float4*)(ws + (58u << 20));
  __hip_bfloat16* Wb = (__hip_bfloat16*)(ws + (64u << 20));
  if (ws_size < (65u << 20)) return;

  k_prep<<<dim3(136), dim3(256), 0, stream>>>(lam_re, lam_im, p_re, p_im,
                                              B_re, B_im, Ct_re, Ct_im, wtab, otab);
  k_mega<<<dim3(2048 + 8192 + 1024), dim3(256), 0, stream>>>(
      wtab, otab, log_step, atr, u, ut, W, Wb);
  k_fftK<<<dim3(DM), dim3(256), 0, stream>>>(atr, Kf);
  k_conv<<<dim3((NB/2) * DM), dim3(256), 0, stream>>>(ut, Kf, Dv, zbt);
  k_gemm_ln<<<dim3(MTOK/64), dim3(512), 0, stream>>>((const ushort*)zbt, (const short*)Wb,
                                                     bias, u, ln_w, ln_b, out);
}

// Round 12
// 124.777 us; speedup vs baseline: 1.3084x; 1.3084x over previous
//
#include <hip/hip_runtime.h>
#include <hip/hip_bf16.h>
#include <math.h>

#define PI_F 3.14159265358979f

typedef __attribute__((ext_vector_type(8))) short bf16x8;   // 8 bf16
typedef __attribute__((ext_vector_type(4))) float f32x4;
typedef __attribute__((ext_vector_type(2))) float f32x2;

#define DM 512
#define LSEQ 2048
#define NB 8
#define NFFT 4096
#define MTOK (NB*LSEQ)

__device__ __forceinline__ float frcp(float x) { return __builtin_amdgcn_rcpf(x); }

// Exact-enough GELU: tanh form, tanh via v_exp. |err vs erf-GELU| <~ 1e-3.
__device__ __forceinline__ float gelu_fast(float y) {
  float t = 0.79788456f * (y + 0.044715f * y * y * y);
  float e = __expf(2.0f * t);
  float th = 1.0f - 2.0f * frcp(e + 1.0f);
  return 0.5f * y * (1.0f + th);
}

// Padded LDS index (split f32 arrays): +1 word per 32.
__device__ __forceinline__ int PD(int i) { return i + (i >> 5); }
#define LDSN 4224   // PD(4095)=4222

// ---------------- 8-point DFT in registers (proven r2-r10) ----------------
template<bool INV>
__device__ __forceinline__ void dft8(const float xr[8], const float xi[8],
                                     float yr[8], float yi[8]) {
  const float C = 0.70710678118654752f;
  float t0r=xr[0]+xr[4], t0i=xi[0]+xi[4];
  float t1r=xr[0]-xr[4], t1i=xi[0]-xi[4];
  float t2r=xr[2]+xr[6], t2i=xi[2]+xi[6];
  float t3r=xr[2]-xr[6], t3i=xi[2]-xi[6];
  float it3r = INV ? -t3i : t3i;
  float it3i = INV ?  t3r : -t3r;
  float E0r=t0r+t2r, E0i=t0i+t2i;
  float E2r=t0r-t2r, E2i=t0i-t2i;
  float E1r=t1r+it3r, E1i=t1i+it3i;
  float E3r=t1r-it3r, E3i=t1i-it3i;
  float u0r=xr[1]+xr[5], u0i=xi[1]+xi[5];
  float u1r=xr[1]-xr[5], u1i=xi[1]-xi[5];
  float u2r=xr[3]+xr[7], u2i=xi[3]+xi[7];
  float u3r=xr[3]-xr[7], u3i=xi[3]-xi[7];
  float iu3r = INV ? -u3i : u3i;
  float iu3i = INV ?  u3r : -u3r;
  float O0r=u0r+u2r, O0i=u0i+u2i;
  float O2r=u0r-u2r, O2i=u0i-u2i;
  float O1r=u1r+iu3r, O1i=u1i+iu3i;
  float O3r=u1r-iu3r, O3i=u1i-iu3i;
  float w1r = INV ? C*(O1r-O1i) : C*(O1r+O1i);
  float w1i = INV ? C*(O1r+O1i) : C*(O1i-O1r);
  float w2r = INV ? -O2i : O2i;
  float w2i = INV ?  O2r : -O2r;
  float w3r = INV ? -C*(O3r+O3i) : C*(O3i-O3r);
  float w3i = INV ?  C*(O3r-O3i) : -C*(O3r+O3i);
  yr[0]=E0r+O0r; yi[0]=E0i+O0i;
  yr[4]=E0r-O0r; yi[4]=E0i-O0i;
  yr[1]=E1r+w1r; yi[1]=E1i+w1i;
  yr[5]=E1r-w1r; yi[5]=E1i-w1i;
  yr[2]=E2r+w2r; yi[2]=E2i+w2i;
  yr[6]=E2r-w2r; yi[6]=E2i-w2i;
  yr[3]=E3r+w3r; yi[3]=E3i+w3i;
  yr[7]=E3r-w3r; yi[7]=E3i-w3i;
}

// ---------------- 16-point DFT = 2 x dft8 + combine ----------------
template<bool INV>
__device__ __forceinline__ void dft16(const float xr[16], const float xi[16],
                                      float yr[16], float yi[16]) {
  float exr[8], exi[8], oxr[8], oxi[8];
  #pragma unroll
  for (int m = 0; m < 8; ++m) {
    exr[m]=xr[2*m];   exi[m]=xi[2*m];
    oxr[m]=xr[2*m+1]; oxi[m]=xi[2*m+1];
  }
  float er[8], ei[8], orr[8], oii[8];
  dft8<INV>(exr, exi, er, ei);
  dft8<INV>(oxr, oxi, orr, oii);
  const float KC = 0.92387953251128675f;
  const float KS = 0.38268343236508977f;
  const float KH = 0.70710678118654752f;
  float tr, ti;
  yr[0]=er[0]+orr[0]; yi[0]=ei[0]+oii[0];
  yr[8]=er[0]-orr[0]; yi[8]=ei[0]-oii[0];
  { float a=KC, b=INV?KS:-KS;
    tr=orr[1]*a-oii[1]*b; ti=orr[1]*b+oii[1]*a;
    yr[1]=er[1]+tr; yi[1]=ei[1]+ti; yr[9]=er[1]-tr; yi[9]=ei[1]-ti; }
  { float a=KH, b=INV?KH:-KH;
    tr=orr[2]*a-oii[2]*b; ti=orr[2]*b+oii[2]*a;
    yr[2]=er[2]+tr; yi[2]=ei[2]+ti; yr[10]=er[2]-tr; yi[10]=ei[2]-ti; }
  { float a=KS, b=INV?KC:-KC;
    tr=orr[3]*a-oii[3]*b; ti=orr[3]*b+oii[3]*a;
    yr[3]=er[3]+tr; yi[3]=ei[3]+ti; yr[11]=er[3]-tr; yi[11]=ei[3]-ti; }
  { if (INV) { tr=-oii[4]; ti= orr[4]; } else { tr= oii[4]; ti=-orr[4]; }
    yr[4]=er[4]+tr; yi[4]=ei[4]+ti; yr[12]=er[4]-tr; yi[12]=ei[4]-ti; }
  { float a=-KS, b=INV?KC:-KC;
    tr=orr[5]*a-oii[5]*b; ti=orr[5]*b+oii[5]*a;
    yr[5]=er[5]+tr; yi[5]=ei[5]+ti; yr[13]=er[5]-tr; yi[13]=ei[5]-ti; }
  { float a=-KH, b=INV?KH:-KH;
    tr=orr[6]*a-oii[6]*b; ti=orr[6]*b+oii[6]*a;
    yr[6]=er[6]+tr; yi[6]=ei[6]+ti; yr[14]=er[6]-tr; yi[14]=ei[6]-ti; }
  { float a=-KC, b=INV?KS:-KS;
    tr=orr[7]*a-oii[7]*b; ti=orr[7]*b+oii[7]*a;
    yr[7]=er[7]+tr; yi[7]=ei[7]+ti; yr[15]=er[7]-tr; yi[15]=ei[7]-ti; }
}

// ---------------- Stockham radix-16 stage (chain twiddle -- proven form) ---
// NOTE r11 lesson: precomputed twiddle ARRAYS passed by pointer land in
// scratch (rule #20) -> 125 MB of spill traffic. Keep the in-stage chain.
template<bool INV, int NSLOG, int NBF>
__device__ __forceinline__ void r16s(float* sr, float* si, int tid,
                                     float c1, float s1f) {
  float yr[16], yi[16];
  bool act = (NBF >= 256) || (tid < NBF);
  __syncthreads();
  if (act) {
    float xr[16], xi[16];
    #pragma unroll
    for (int m = 0; m < 16; ++m) {
      int ix = PD(tid + m * NBF);
      xr[m] = sr[ix]; xi[m] = si[ix];
    }
    if (NSLOG > 0) {
      float s1 = INV ? -s1f : s1f;
      float wr = c1, wi = s1;
      #pragma unroll
      for (int m = 1; m < 16; ++m) {
        float tr = xr[m]*wr - xi[m]*wi;
        float ti = xr[m]*wi + xi[m]*wr;
        xr[m] = tr; xi[m] = ti;
        float nr = wr*c1 - wi*s1;
        float ni = wr*s1 + wi*c1;
        wr = nr; wi = ni;
      }
    }
    dft16<INV>(xr, xi, yr, yi);
  }
  __syncthreads();
  if (act) {
    int r = tid & ((1 << NSLOG) - 1);
    int q = tid >> NSLOG;
    int base = (q << (NSLOG + 4)) + r;
    #pragma unroll
    for (int p = 0; p < 16; ++p) {
      int ix = PD(base + (p << NSLOG));
      sr[ix] = yr[p]; si[ix] = yi[p];
    }
  }
}

// ---- Stage 0 of a FORWARD 4096 FFT whose inputs [2048,4096) are ZERO ----
__device__ __forceinline__ void r16s_zfirst(float* sr, float* si, int tid) {
  const float KC = 0.92387953251128675f;
  const float KS = 0.38268343236508977f;
  const float KH = 0.70710678118654752f;
  float xr[8], xi[8];
  __syncthreads();
  #pragma unroll
  for (int m = 0; m < 8; ++m) {
    int ix = PD(tid + m * 256);
    xr[m] = sr[ix]; xi[m] = si[ix];
  }
  float er[8], ei[8];
  dft8<false>(xr, xi, er, ei);
  float tr[8], ti[8];
  tr[0] = xr[0];                      ti[0] = xi[0];
  tr[1] =  xr[1]*KC + xi[1]*KS;       ti[1] =  xi[1]*KC - xr[1]*KS;
  tr[2] = (xr[2] + xi[2])*KH;         ti[2] = (xi[2] - xr[2])*KH;
  tr[3] =  xr[3]*KS + xi[3]*KC;       ti[3] =  xi[3]*KS - xr[3]*KC;
  tr[4] =  xi[4];                     ti[4] = -xr[4];
  tr[5] = -xr[5]*KS + xi[5]*KC;       ti[5] = -xi[5]*KS - xr[5]*KC;
  tr[6] = (xi[6] - xr[6])*KH;         ti[6] = -(xr[6] + xi[6])*KH;
  tr[7] = -xr[7]*KC + xi[7]*KS;       ti[7] = -xi[7]*KC - xr[7]*KS;
  float odr[8], odi[8];
  dft8<false>(tr, ti, odr, odi);
  __syncthreads();
  int base = tid << 4;
  #pragma unroll
  for (int j = 0; j < 8; ++j) {
    int ie = PD(base + 2*j), io = PD(base + 2*j + 1);
    sr[ie] = er[j];  si[ie] = ei[j];
    sr[io] = odr[j]; si[io] = odi[j];
  }
}

// ---------------- Stockham radix-8 stage (256-thread blocks) --------------
template<bool INV, int NSLOG, int NBF>
__device__ __forceinline__ void r8s(float* sr, float* si, int tid,
                                    float c1, float s1f) {
  float yr[8], yi[8];
  bool act = (NBF >= 256) || (tid < NBF);
  __syncthreads();
  if (act) {
    float xr[8], xi[8];
    #pragma unroll
    for (int m = 0; m < 8; ++m) {
      int ix = PD(tid + m * NBF);
      xr[m] = sr[ix]; xi[m] = si[ix];
    }
    if (NSLOG > 0) {
      float s1 = INV ? -s1f : s1f;
      float wr = c1, wi = s1;
      #pragma unroll
      for (int m = 1; m < 8; ++m) {
        float tr = xr[m]*wr - xi[m]*wi;
        float ti = xr[m]*wi + xi[m]*wr;
        xr[m] = tr; xi[m] = ti;
        float nr = wr*c1 - wi*s1;
        float ni = wr*s1 + wi*c1;
        wr = nr; wi = ni;
      }
    }
    dft8<INV>(xr, xi, yr, yi);
  }
  __syncthreads();
  if (act) {
    int r = tid & ((1 << NSLOG) - 1);
    int q = tid >> NSLOG;
    int base = (q << (NSLOG + 3)) + r;
    #pragma unroll
    for (int p = 0; p < 8; ++p) {
      int ix = PD(base + (p << NSLOG));
      sr[ix] = yr[p]; si[ix] = yi[p];
    }
  }
}

// 4096 = 16*16*16, 256 threads (full input)
template<bool INV>
__device__ __forceinline__ void fft4096(float* sr, float* si, int tid,
                                        float cA, float sA, float cB, float sB) {
  r16s<INV, 0, 256>(sr, si, tid, 1.f, 0.f);
  r16s<INV, 4, 256>(sr, si, tid, cA, sA);
  r16s<INV, 8, 256>(sr, si, tid, cB, sB);
  __syncthreads();
}

// forward 4096 with inputs [2048,4096) == 0 (never read)
__device__ __forceinline__ void fft4096z(float* sr, float* si, int tid,
                                         float cA, float sA, float cB, float sB) {
  r16s_zfirst(sr, si, tid);
  r16s<false, 4, 256>(sr, si, tid, cA, sA);
  r16s<false, 8, 256>(sr, si, tid, cB, sB);
  __syncthreads();
}

// 2048 = 8*16*16, 256 threads
template<bool INV>
__device__ __forceinline__ void fft2048(float* sr, float* si, int tid,
                                        float cA, float sA, float cB, float sB) {
  r8s <INV, 0, 256>(sr, si, tid, 1.f, 0.f);
  r16s<INV, 3, 128>(sr, si, tid, cA, sA);
  r16s<INV, 7, 128>(sr, si, tid, cB, sB);
  __syncthreads();
}

// ---------------- Kernel 0: wtab prep + omega table ------------------------
// otab[l] = (cr, ci, gbr, gbi): c = 2/(1+w), g = (2/step)*(gbr,gbi).
// PRECISE sincosf (Nyquist l=1024 NaN trap -- round 3).
__global__ __launch_bounds__(256) void k_prep(
    const float* __restrict__ lam_re, const float* __restrict__ lam_im,
    const float* __restrict__ p_re,   const float* __restrict__ p_im,
    const float* __restrict__ B_re,   const float* __restrict__ B_im,
    const float* __restrict__ Ct_re,  const float* __restrict__ Ct_im,
    float* __restrict__ wtab, float4* __restrict__ otab) {
  int bidx = blockIdx.x;
  if (bidx < 128) {
    int idx = bidx * 256 + threadIdx.x;   // h*64+n
    int n = idx & 63;
    float br = B_re[idx],  bi = B_im[idx];
    float cr = Ct_re[idx], ci = Ct_im[idx];
    float pr = p_re[n],    pi = p_im[n];
    float* w = wtab + (size_t)idx * 12;
    w[0] = cr*br + ci*bi;   w[1] = cr*bi - ci*br;
    w[2] = cr*pr + ci*pi;   w[3] = cr*pi - ci*pr;
    w[4] = pr*br + pi*bi;   w[5] = pr*bi - pi*br;
    w[6] = pr*pr + pi*pi;   w[7] = lam_re[n];
    w[8] = lam_im[n];       w[9] = 0.f; w[10] = 0.f; w[11] = 0.f;
  } else {
    int l = (bidx - 128) * 256 + threadIdx.x;   // [0,2048)
    float omi, omr;
    sincosf(-2.0f * PI_F * (float)l / (float)LSEQ, &omi, &omr);
    float a = 1.0f + omr;
    float iv = frcp(a*a + omi*omi);
    float4 o;
    o.x = 2.0f * a * iv;                        // cr
    o.y = -2.0f * omi * iv;                     // ci
    o.z = (1.0f - omr*omr - omi*omi) * iv;      // g base re
    o.w = (-2.0f * omi) * iv;                   // g base im
    otab[l] = o;
  }
}

// ---------------- Mega kernel: cauchy | tr_u | W cast (heterogeneous) ------
__global__ __launch_bounds__(256) void k_mega(
    const float* __restrict__ wtab, const float4* __restrict__ otab,
    const float* __restrict__ log_step, float2* __restrict__ atr,
    const float* __restrict__ u, float* __restrict__ ut,
    const float* __restrict__ W, __hip_bfloat16* __restrict__ Wb) {
  __shared__ float tsh[32][33];
  int bidx = blockIdx.x;
  int tid = threadIdx.x;
  if (bidx < 2048) {
    // ---- Cauchy sums, l-pair packed in f32x2 lanes ----
    int h = bidx >> 2;
    int l0 = ((bidx & 3) << 8) + tid;   // [0,1024)
    int l1 = l0 + 1024;
    float tos = 2.0f * expf(-log_step[h]);
    float4 o0 = otab[l0];
    float4 o1 = otab[l1];
    float cr0 = o0.x, ci0 = o0.y, cr1 = o1.x, ci1 = o1.y;
    f32x2 gr, gi;
    gr.x = tos * o0.z;  gr.y = tos * o1.z;
    gi.x = tos * o0.w;  gi.y = tos * o1.w;
    f32x2 K00r={0.f,0.f},K00i={0.f,0.f},K01r={0.f,0.f},K01i={0.f,0.f},
          K10r={0.f,0.f},K10i={0.f,0.f},K11r={0.f,0.f},K11i={0.f,0.f};
    const float4* wq = (const float4*)(wtab + (size_t)h * 64 * 12);
    #pragma unroll 8
    for (int n = 0; n < 64; ++n) {
      float4 wa = wq[n*3+0];
      float4 wb = wq[n*3+1];
      float  lim = wq[n*3+2].x;
      f32x2 dr = gr - wb.w;
      f32x2 di = gi - lim;
      f32x2 den = dr*dr + di*di;
      // paired reciprocal: 1 trans op for both lanes
      float ip = frcp(den.x * den.y);
      f32x2 inv; inv.x = den.y * ip; inv.y = den.x * ip;
      f32x2 car = dr*inv, cai = -di*inv;
      K00r += wa.x*car - wa.y*cai;  K00i += wa.x*cai + wa.y*car;
      K01r += wa.z*car - wa.w*cai;  K01i += wa.z*cai + wa.w*car;
      K10r += wb.x*car - wb.y*cai;  K10i += wb.x*cai + wb.y*car;
      K11r += wb.z*car;             K11i += wb.z*cai;
    }
    {
      float tr = K01r.x*K10r.x - K01i.x*K10i.x, ti = K01r.x*K10i.x + K01i.x*K10r.x;
      float d1r = 1.0f + K11r.x, d1i = K11i.x;
      float invd1 = frcp(d1r*d1r + d1i*d1i);
      float t2r = (tr*d1r + ti*d1i) * invd1;
      float t2i = (ti*d1r - tr*d1i) * invd1;
      float numr = K00r.x - t2r, numi = K00i.x - t2i;
      atr[(size_t)h * LSEQ + l0] = make_float2(cr0*numr - ci0*numi, cr0*numi + ci0*numr);
    }
    {
      float tr = K01r.y*K10r.y - K01i.y*K10i.y, ti = K01r.y*K10i.y + K01i.y*K10r.y;
      float d1r = 1.0f + K11r.y, d1i = K11i.y;
      float invd1 = frcp(d1r*d1r + d1i*d1i);
      float t2r = (tr*d1r + ti*d1i) * invd1;
      float t2i = (ti*d1r - tr*d1i) * invd1;
      float numr = K00r.y - t2r, numi = K00i.y - t2i;
      atr[(size_t)h * LSEQ + l1] = make_float2(cr1*numr - ci1*numi, cr1*numi + ci1*numr);
    }
  } else if (bidx < 2048 + 8192) {
    // ---- transpose u (B,L,D) -> ut (B,D,L), 32x32 tiles ----
    int t = bidx - 2048;
    int lx = t & 63, hy = (t >> 6) & 15, b = t >> 10;
    int l0 = lx * 32, h0 = hy * 32;
    int x = tid & 31, y0 = tid >> 5;
    #pragma unroll
    for (int i = 0; i < 4; ++i) {
      int y = y0 + i*8;
      tsh[y][x] = u[((size_t)b*LSEQ + l0 + y) * DM + h0 + x];
    }
    __syncthreads();
    #pragma unroll
    for (int i = 0; i < 4; ++i) {
      int y = y0 + i*8;
      ut[((size_t)b*DM + h0 + y) * LSEQ + l0 + x] = tsh[x][y];
    }
  } else {
    int i = (bidx - 10240) * 256 + tid;
    Wb[i] = __float2bfloat16(W[i]);
  }
}

// ---------------- Kernel 1b: ifft2048 -> pad -> fft4096 -> Kf --------------
__global__ __launch_bounds__(256, 4) void k_fftK(const float2* __restrict__ atr,
                                                 float2* __restrict__ Kf) {
  __shared__ float sr[LDSN], si[LDSN];
  int h = blockIdx.x, tid = threadIdx.x;
  float c2a, s2a, c2b, s2b, c4a, s4a, c4b, s4b;
  { int r = tid & 7;   __sincosf(-2.f*PI_F*(float)r/128.f,  &s2a, &c2a); }
  { int r = tid & 127; __sincosf(-2.f*PI_F*(float)r/2048.f, &s2b, &c2b); }
  { int r = tid & 15;  __sincosf(-2.f*PI_F*(float)r/256.f,  &s4a, &c4a); }
  { int r = tid;       __sincosf(-2.f*PI_F*(float)r/4096.f, &s4b, &c4b); }
  const float2* ap = atr + (size_t)h * LSEQ;
  #pragma unroll
  for (int i = 0; i < 8; ++i) {
    int l = tid + i*256;
    float2 v = ap[l];
    sr[PD(l)] = v.x; si[PD(l)] = v.y;
  }
  fft2048<true>(sr, si, tid, c2a, s2a, c2b, s2b);
  #pragma unroll
  for (int i = 0; i < 8; ++i) {
    int m = tid + i*256;
    float v = sr[PD(m)] * (1.0f / (float)LSEQ);
    sr[PD(m)] = v;
    si[PD(m)] = 0.0f;
  }
  fft4096z(sr, si, tid, c4a, s4a, c4b, s4b);
  float2* ko = Kf + (size_t)h * NFFT;
  #pragma unroll
  for (int i = 0; i < 16; ++i) {
    int f = tid + i*256;
    ko[f] = make_float2(sr[PD(f)], si[PD(f)]);
  }
}

// ---------------- Kernel 3: FFT conv + D*u + GELU -> zbt (bf16) -----------
// wg = (batch-pair, channel): pack u[b0,h] + i*u[b1,h], single shared K.
// (round-10 proven form: chain twiddles, no cached tw arrays)
__global__ __launch_bounds__(256, 4) void k_conv(const float* __restrict__ ut,
                                                 const float2* __restrict__ Kf,
                                                 const float* __restrict__ Dvec,
                                                 __hip_bfloat16* __restrict__ zbt) {
  __shared__ float sr[LDSN], si[LDSN];
  int wg = blockIdx.x;
  int bp = wg >> 9, h = wg & 511;
  int b0 = bp*2, b1 = bp*2 + 1;
  int tid = threadIdx.x;
  float c4a, s4a, c4b, s4b;
  { int r = tid & 15; __sincosf(-2.f*PI_F*(float)r/256.f,  &s4a, &c4a); }
  { int r = tid;      __sincosf(-2.f*PI_F*(float)r/4096.f, &s4b, &c4b); }
  const float* u0p = ut + ((size_t)(b0*DM + h)) * LSEQ;
  const float* u1p = ut + ((size_t)(b1*DM + h)) * LSEQ;
  #pragma unroll
  for (int i = 0; i < 8; ++i) {
    int l = tid + i*256;
    sr[PD(l)] = u0p[l];  si[PD(l)] = u1p[l];
  }
  fft4096z(sr, si, tid, c4a, s4a, c4b, s4b);
  float yrg[16], yig[16];
  const float2* kp = Kf + (size_t)h * NFFT;
  #pragma unroll
  for (int i = 0; i < 16; ++i) {
    int f = tid + i*256;
    int fn = (NFFT - f) & (NFFT - 1);
    float ar = sr[PD(f)],  ai = si[PD(f)];
    float br = sr[PD(fn)], bi = -si[PD(fn)];
    float u0r = 0.5f*(ar + br), u0i = 0.5f*(ai + bi);
    float u1r = 0.5f*(ai - bi), u1i = -0.5f*(ar - br);
    float2 K0 = kp[f];
    float y0r = u0r*K0.x - u0i*K0.y, y0i = u0r*K0.y + u0i*K0.x;
    float y1r = u1r*K0.x - u1i*K0.y, y1i = u1r*K0.y + u1i*K0.x;
    yrg[i] = y0r - y1i;
    yig[i] = y0i + y1r;
  }
  __syncthreads();
  #pragma unroll
  for (int i = 0; i < 16; ++i) {
    int f = tid + i*256;
    sr[PD(f)] = yrg[i]; si[PD(f)] = yig[i];
  }
  fft4096<true>(sr, si, tid, c4a, s4a, c4b, s4b);
  float d = Dvec[h];
  __hip_bfloat16* zb0 = zbt + ((size_t)(b0*DM + h)) * LSEQ;
  __hip_bfloat16* zb1 = zbt + ((size_t)(b1*DM + h)) * LSEQ;
  const float inv_n = 1.0f / (float)NFFT;
  #pragma unroll
  for (int i = 0; i < 8; ++i) {
    int l = tid + i*256;
    float y0 = sr[PD(l)]*inv_n + d*u0p[l];
    float y1 = si[PD(l)]*inv_n + d*u1p[l];
    zb0[l] = __float2bfloat16(gelu_fast(y0));
    zb1[l] = __float2bfloat16(gelu_fast(y1));
  }
}

// ---------------- Kernel 6: fused GEMM + bias + residual + LayerNorm -------
// 64 tokens x full N=512 per block, 8 waves (2M x 4N). Reads zbt (B,D,L)
// directly with a transposing LDS stage.
__global__ __launch_bounds__(512) void k_gemm_ln(
    const ushort* __restrict__ zbt,   // (B, D, L) bf16
    const short* __restrict__ Wb,     // (O, H) bf16
    const float* __restrict__ bias,
    const float* __restrict__ u,      // (M, D) f32
    const float* __restrict__ lnw, const float* __restrict__ lnb,
    float* __restrict__ out) {
  __shared__ ushort sA[64][40];
  __shared__ short sB[512][40];
  __shared__ float red[2][4][64];
  __shared__ float smu[64], srs[64];
  __shared__ float sln[2][DM];
  int tid = threadIdx.x, wave = tid >> 6, lane = tid & 63;
  int wm = wave >> 2, wn = wave & 3;          // 2 x 4
  int m0 = blockIdx.x * 64;
  int b = m0 >> 11;
  int l0 = m0 & (LSEQ - 1);
  const ushort* zb = zbt + (size_t)b * DM * LSEQ;
  int row = lane & 15, kq8 = (lane >> 4) << 3;
  int kk = tid >> 4, seg = tid & 15;
  int cB = (tid & 3) << 3, rB = tid >> 2;
  sln[0][tid] = lnw[tid];
  sln[1][tid] = lnb[tid];
  f32x4 acc[2][8];
  #pragma unroll
  for (int i = 0; i < 2; ++i)
    #pragma unroll
    for (int j = 0; j < 8; ++j) acc[i][j] = (f32x4){0.f,0.f,0.f,0.f};
  for (int k0 = 0; k0 < DM; k0 += 32) {
    __syncthreads();
    {
      uint2 v = *(const uint2*)(zb + (size_t)(k0 + kk)*LSEQ + l0 + seg*4);
      const ushort* p = (const ushort*)&v;
      sA[seg*4 + 0][kk] = p[0];
      sA[seg*4 + 1][kk] = p[1];
      sA[seg*4 + 2][kk] = p[2];
      sA[seg*4 + 3][kk] = p[3];
    }
    #pragma unroll
    for (int jj = 0; jj < 4; ++jj) {
      int o = rB + jj*128;
      *(uint4*)&sB[o][cB] = *(const uint4*)(Wb + (size_t)o*DM + k0 + cB);
    }
    __syncthreads();
    bf16x8 a0 = *(const bf16x8*)&sA[wm*32 + row][kq8];
    bf16x8 a1 = *(const bf16x8*)&sA[wm*32 + 16 + row][kq8];
    #pragma unroll
    for (int nt = 0; nt < 8; ++nt) {
      bf16x8 bf = *(const bf16x8*)&sB[wn*128 + nt*16 + row][kq8];
      acc[0][nt] = __builtin_amdgcn_mfma_f32_16x16x32_bf16(a0, bf, acc[0][nt], 0, 0, 0);
      acc[1][nt] = __builtin_amdgcn_mfma_f32_16x16x32_bf16(a1, bf, acc[1][nt], 0, 0, 0);
    }
  }
  int ccol = lane & 15, crow = (lane >> 4) << 2;
  #pragma unroll
  for (int rt = 0; rt < 2; ++rt) {
    #pragma unroll
    for (int rr = 0; rr < 4; ++rr) {
      int lr = wm*32 + rt*16 + crow + rr;
      int gr = m0 + lr;
      float ls = 0.f, ls2 = 0.f;
      #pragma unroll
      for (int nt = 0; nt < 8; ++nt) {
        int col = wn*128 + nt*16 + ccol;
        float v = acc[rt][nt][rr] + bias[col] + u[(size_t)gr*DM + col];
        acc[rt][nt][rr] = v;
        ls += v; ls2 += v*v;
      }
      ls  += __shfl_xor(ls, 1);  ls2 += __shfl_xor(ls2, 1);
      ls  += __shfl_xor(ls, 2);  ls2 += __shfl_xor(ls2, 2);
      ls  += __shfl_xor(ls, 4);  ls2 += __shfl_xor(ls2, 4);
      ls  += __shfl_xor(ls, 8);  ls2 += __shfl_xor(ls2, 8);
      if (ccol == 0) { red[0][wn][lr] = ls; red[1][wn][lr] = ls2; }
    }
  }
  __syncthreads();
  if (tid < 64) {
    float s = red[0][0][tid] + red[0][1][tid] + red[0][2][tid] + red[0][3][tid];
    float q = red[1][0][tid] + red[1][1][tid] + red[1][2][tid] + red[1][3][tid];
    float mean = s * (1.0f/(float)DM);
    float var  = q * (1.0f/(float)DM) - mean*mean;
    smu[tid] = mean;
    srs[tid] = rsqrtf(var + 1e-5f);
  }
  __syncthreads();
  #pragma unroll
  for (int rt = 0; rt < 2; ++rt) {
    #pragma unroll
    for (int rr = 0; rr < 4; ++rr) {
      int lr = wm*32 + rt*16 + crow + rr;
      int gr = m0 + lr;
      float mu = smu[lr], rs = srs[lr];
      #pragma unroll
      for (int nt = 0; nt < 8; ++nt) {
        int col = wn*128 + nt*16 + ccol;
        out[(size_t)gr*DM + col] = (acc[rt][nt][rr] - mu) * rs * sln[0][col] + sln[1][col];
      }
    }
  }
}

// ---------------- launch ----------------
extern "C" void kernel_launch(void* const* d_in, const int* in_sizes, int n_in,
                              void* d_out, int out_size, void* d_ws, size_t ws_size,
                              hipStream_t stream) {
  const float* u        = (const float*)d_in[0];
  const float* lam_re   = (const float*)d_in[1];
  const float* lam_im   = (const float*)d_in[2];
  const float* p_re     = (const float*)d_in[3];
  const float* p_im     = (const float*)d_in[4];
  const float* B_re     = (const float*)d_in[5];
  const float* B_im     = (const float*)d_in[6];
  const float* Ct_re    = (const float*)d_in[7];
  const float* Ct_im    = (const float*)d_in[8];
  const float* log_step = (const float*)d_in[9];
  const float* Dv       = (const float*)d_in[10];
  const float* W        = (const float*)d_in[11];
  const float* bias     = (const float*)d_in[12];
  const float* ln_w     = (const float*)d_in[13];
  const float* ln_b     = (const float*)d_in[14];
  float* out = (float*)d_out;
  char* ws = (char*)d_ws;

  // ws: Kf [0,16M) | ut f32 [16,48M) | zbt bf16 [48,64M) | Wb [64,64.5M)
  // atr (8M) + wtab (1.5M) + otab (32K) overlap zbt region (all dead before
  // k_conv writes zbt).
  float2* Kf = (float2*)ws;
  float*  ut = (float*)(ws + (16u << 20));
  __hip_bfloat16* zbt = (__hip_bfloat16*)(ws + (48u << 20));
  float2* atr  = (float2*)(ws + (48u << 20));
  float*  wtab = (float*)(ws + (56u << 20));
  float4* otab = (float4*)(ws + (58u << 20));
  __hip_bfloat16* Wb = (__hip_bfloat16*)(ws + (64u << 20));
  if (ws_size < (65u << 20)) return;

  k_prep<<<dim3(136), dim3(256), 0, stream>>>(lam_re, lam_im, p_re, p_im,
                                              B_re, B_im, Ct_re, Ct_im, wtab, otab);
  k_mega<<<dim3(2048 + 8192 + 1024), dim3(256), 0, stream>>>(
      wtab, otab, log_step, atr, u, ut, W, Wb);
  k_fftK<<<dim3(DM), dim3(256), 0, stream>>>(atr, Kf);
  k_conv<<<dim3((NB/2) * DM), dim3(256), 0, stream>>>(ut, Kf, Dv, zbt);
  k_gemm_ln<<<dim3(MTOK/64), dim3(512), 0, stream>>>((const ushort*)zbt, (const short*)Wb,
                                                     bias, u, ln_w, ln_b, out);
}